// Round 2
// baseline (976.491 us; speedup 1.0000x reference)
//
#include <hip/hip_runtime.h>

#define NL   8
#define DIM  2048
#define NH   8
#define NKV  2
#define HD   256
#define KVL  4096
#define FFI  8192
#define PLD  256
#define POS  2047
#define NCH  16    // attention chunks over 2048 valid positions
#define CP   128   // positions per chunk

__device__ __forceinline__ float dot4(float4 a, float4 b){
  return a.x*b.x + a.y*b.y + a.z*b.z + a.w*b.w;
}

__device__ __forceinline__ float waveAllSum(float v){
#pragma unroll
  for(int o=1;o<64;o<<=1) v += __shfl_xor(v,o,64);
  return v;
}

__device__ __forceinline__ float waveAllMax(float v){
#pragma unroll
  for(int o=1;o<64;o<<=1) v = fmaxf(v, __shfl_xor(v,o,64));
  return v;
}

__device__ __forceinline__ float blockSum256(float v, float* red){
  int lane = threadIdx.x & 63, w = threadIdx.x >> 6;
  v = waveAllSum(v);
  __syncthreads();
  if(lane==0) red[w] = v;
  __syncthreads();
  return red[0]+red[1]+red[2]+red[3];
}

__device__ __forceinline__ float gelu_tanh(float v){
  return 0.5f*v*(1.0f + tanhf(0.7978845608028654f*(v + 0.044715f*v*v*v)));
}

// ---- qkv GEMV with fused post_pl (prev layer) / initial prologue ----
// prologue: h4 = (hC + rms(u)*g_pl)*ls   (or h4 = hidden for layer 0)
//           x  = rms(h4)*g_in ; block0 persists h4 -> hA
__global__ __launch_bounds__(256) void qkv_k(
    const float* __restrict__ Wq, const float* __restrict__ Wk,
    const float* __restrict__ Wv,
    const float* __restrict__ hC, const float* __restrict__ u,
    const float* __restrict__ g_pl, const float* __restrict__ lsc,
    const float* __restrict__ g_in, const float* __restrict__ hidden,
    float* __restrict__ hA, float* __restrict__ qkv){
  __shared__ float xs[DIM];
  __shared__ float red[4];
  int tid = threadIdx.x;
  float hv[8];
  if(hidden){
#pragma unroll
    for(int i=0;i<8;i++) hv[i] = hidden[tid + i*256];
  } else {
    float uv[8]; float ss1 = 0.f;
#pragma unroll
    for(int i=0;i<8;i++){ uv[i] = u[tid + i*256]; ss1 += uv[i]*uv[i]; }
    ss1 = blockSum256(ss1, red);
    float r1 = rsqrtf(ss1*(1.f/DIM) + 1e-6f);
    float ls = lsc[0];
#pragma unroll
    for(int i=0;i<8;i++){
      int idx = tid + i*256;
      hv[i] = (hC[idx] + uv[i]*r1*g_pl[idx])*ls;
    }
  }
  float ss2 = 0.f;
#pragma unroll
  for(int i=0;i<8;i++) ss2 += hv[i]*hv[i];
  ss2 = blockSum256(ss2, red);
  float r2 = rsqrtf(ss2*(1.f/DIM) + 1e-6f);
#pragma unroll
  for(int i=0;i<8;i++){
    int idx = tid + i*256;
    xs[idx] = hv[i]*r2*g_in[idx];
    if(blockIdx.x==0) hA[idx] = hv[i];
  }
  __syncthreads();
  int lane = tid & 63, wv = tid >> 6;
  int r = blockIdx.x*4 + wv;
  const float* W; int row;
  if(r < 2048){ W = Wq; row = r; }
  else if(r < 2560){ W = Wk; row = r - 2048; }
  else { W = Wv; row = r - 2560; }
  const float4* Wr = (const float4*)(W + (size_t)row*DIM);
  const float4* xs4 = (const float4*)xs;
  float acc = 0.f;
#pragma unroll
  for(int i=0;i<DIM/256;i++) acc += dot4(Wr[lane + i*64], xs4[lane + i*64]);
  acc = waveAllSum(acc);
  if(lane==0) qkv[r] = acc;
}

// ---- normalize+rope one 256-vector with one wave; returns this lane's float4 ----
__device__ __forceinline__ float4 normRope(const float* __restrict__ raw, int lane,
    const float* __restrict__ gain, const float* __restrict__ cosT,
    const float* __restrict__ sinT, bool doRope){
  float4 v4 = ((const float4*)raw)[lane];
  float ss = waveAllSum(dot4(v4,v4));
  float sc = rsqrtf(ss*(1.f/HD) + 1e-6f);
  float4 n;
  if(gain){
    float4 g4 = ((const float4*)gain)[lane];
    n.x=v4.x*sc*g4.x; n.y=v4.y*sc*g4.y; n.z=v4.z*sc*g4.z; n.w=v4.w*sc*g4.w;
  } else {
    n.x=v4.x*sc; n.y=v4.y*sc; n.z=v4.z*sc; n.w=v4.w*sc;
  }
  if(!doRope) return n;
  float4 np;
  np.x=__shfl_xor(n.x,32,64); np.y=__shfl_xor(n.y,32,64);
  np.z=__shfl_xor(n.z,32,64); np.w=__shfl_xor(n.w,32,64);
  float4 c4 = ((const float4*)cosT)[lane];
  float4 s4 = ((const float4*)sinT)[lane];
  float sg = (lane < 32) ? -1.f : 1.f;
  float4 o;
  o.x = n.x*c4.x + sg*np.x*s4.x;
  o.y = n.y*c4.y + sg*np.y*s4.y;
  o.z = n.z*c4.z + sg*np.z*s4.z;
  o.w = n.w*c4.w + sg*np.w*s4.w;
  return o;
}

// ---- attention partials with fused q/k/v norm+rope.
// blocks [0, NKV*NCH): (kv, chunk) partial flash attention
// block NKV*NCH: writes normalized k/v rows at POS into the output caches
__global__ __launch_bounds__(256) void attn_k(
    const float* __restrict__ qkv,
    const float* __restrict__ gq, const float* __restrict__ gk,
    const float* __restrict__ cosT, const float* __restrict__ sinT,
    float* __restrict__ Kc, float* __restrict__ Vc,
    float* __restrict__ pm, float* __restrict__ pl, float* __restrict__ po){
  int b = blockIdx.x;
  int tid = threadIdx.x, lane = tid & 63, wv = tid >> 6;

  if(b == NKV*NCH){ // cache-row writer: wave -> (kv, k|v)
    int kvv = wv >> 1, isV = wv & 1;
    const float* raw = qkv + (isV ? 2560 : 2048) + kvv*HD;
    float4 o = normRope(raw, lane, isV ? nullptr : gk, cosT, sinT, !isV);
    float* dst = (isV ? Vc : Kc) + ((size_t)kvv*KVL + POS)*HD;
    ((float4*)dst)[lane] = o;
    return;
  }

  int kv = b >> 4, c = b & (NCH-1);
  __shared__ float q_s[4][HD];
  __shared__ float kf[HD], vf[HD];
  __shared__ float s_s[4][CP];
  __shared__ float s_w[4][CP];

  { // q norm+rope: wave wv handles head kv*4+wv
    float4 o = normRope(qkv + (kv*4 + wv)*HD, lane, gq, cosT, sinT, true);
    ((float4*)q_s[wv])[lane] = o;
  }
  bool fresh = (c == NCH-1);
  if(fresh){
    if(wv == 0){
      float4 o = normRope(qkv + 2048 + kv*HD, lane, gk, cosT, sinT, true);
      ((float4*)kf)[lane] = o;
    } else if(wv == 1){
      float4 o = normRope(qkv + 2560 + kv*HD, lane, nullptr, cosT, sinT, false);
      ((float4*)vf)[lane] = o;
    }
  }
  __syncthreads();

  float4 q4[4];
#pragma unroll
  for(int hh=0;hh<4;hh++) q4[hh] = ((const float4*)q_s[hh])[lane];
  const float4* Kp = (const float4*)(Kc + ((size_t)kv*KVL + c*CP)*HD);
  for(int j=0;j<CP/4;j++){
    int p = wv*(CP/4) + j;
    float4 k4 = (fresh && p==CP-1) ? ((const float4*)kf)[lane]
                                   : Kp[(size_t)p*64 + lane];
    float d0 = dot4(k4,q4[0]), d1 = dot4(k4,q4[1]);
    float d2 = dot4(k4,q4[2]), d3 = dot4(k4,q4[3]);
    d0 = waveAllSum(d0); d1 = waveAllSum(d1);
    d2 = waveAllSum(d2); d3 = waveAllSum(d3);
    if(lane==0){ s_s[0][p]=d0; s_s[1][p]=d1; s_s[2][p]=d2; s_s[3][p]=d3; }
  }
  __syncthreads();

  { // per-head partial softmax: wave wv = head wv
    float s0 = s_s[wv][lane], s1 = s_s[wv][lane+64];
    float m = waveAllMax(fmaxf(s0,s1));
    float e0 = __expf(s0-m), e1 = __expf(s1-m);
    s_w[wv][lane] = e0; s_w[wv][lane+64] = e1;
    float lsum = waveAllSum(e0+e1);
    if(lane==0){
      int hg = kv*4 + wv;
      pm[hg*NCH + c] = m;
      pl[hg*NCH + c] = lsum;
    }
  }
  __syncthreads();

  float acc[4] = {0.f,0.f,0.f,0.f};
  const float* Vp = Vc + ((size_t)kv*KVL + c*CP)*HD;
  for(int p=0;p<CP;p++){
    float vv = (fresh && p==CP-1) ? vf[tid] : Vp[(size_t)p*HD + tid];
#pragma unroll
    for(int hh=0;hh<4;hh++) acc[hh] += s_w[hh][p]*vv;
  }
#pragma unroll
  for(int hh=0;hh<4;hh++){
    int hg = kv*4 + hh;
    po[((size_t)hg*NCH + c)*HD + tid] = acc[hh];
  }
}

// ---- w_o GEMV with fused chunk-combine prologue ----
__global__ __launch_bounds__(256) void wo_k(const float* __restrict__ W,
    const float* __restrict__ pm, const float* __restrict__ pl,
    const float* __restrict__ po, float* __restrict__ y){
  __shared__ float ao_s[DIM];
  __shared__ float se_s[NH][NCH];
  __shared__ float Ms[NH];
  __shared__ float Li[NH];
  int tid = threadIdx.x;
  if(tid < NH){
    float m = -1e30f;
    for(int c=0;c<NCH;c++) m = fmaxf(m, pm[tid*NCH+c]);
    Ms[tid] = m;
  }
  __syncthreads();
  if(tid < NH*NCH){
    int h = tid >> 4, c = tid & (NCH-1);
    se_s[h][c] = __expf(pm[h*NCH+c] - Ms[h]);
  }
  __syncthreads();
  if(tid < NH){
    float L = 0.f;
    for(int c=0;c<NCH;c++) L += pl[tid*NCH+c]*se_s[tid][c];
    Li[tid] = 1.f/L;
  }
  __syncthreads();
  for(int h=0;h<NH;h++){
    float a = 0.f;
#pragma unroll
    for(int c=0;c<NCH;c++) a += po[((size_t)h*NCH+c)*HD + tid]*se_s[h][c];
    ao_s[h*HD + tid] = a*Li[h];
  }
  __syncthreads();
  int lane = tid & 63, wv = tid >> 6;
  int r = blockIdx.x*4 + wv;
  const float4* Wr = (const float4*)(W + (size_t)r*DIM);
  const float4* xs4 = (const float4*)ao_s;
  float acc = 0.f;
#pragma unroll
  for(int i=0;i<DIM/256;i++) acc += dot4(Wr[lane + i*64], xs4[lane + i*64]);
  acc = waveAllSum(acc);
  if(lane==0) y[r] = acc;
}

// ---- gate/up GEMV with fused post_attn prologue ----
// hB = hA + rms(y)*g_pa ; xm = rms(hB)*g_pf ; block0 persists hB
__global__ __launch_bounds__(256) void gateup_k(const float* __restrict__ Wg,
    const float* __restrict__ Wu, const float* __restrict__ y,
    const float* __restrict__ hA, const float* __restrict__ g_pa,
    const float* __restrict__ g_pf, float* __restrict__ hB, float* __restrict__ t){
  __shared__ float xs[DIM];
  __shared__ float red[4];
  int tid = threadIdx.x;
  float yv[8]; float ss1 = 0.f;
#pragma unroll
  for(int i=0;i<8;i++){ yv[i] = y[tid + i*256]; ss1 += yv[i]*yv[i]; }
  ss1 = blockSum256(ss1, red);
  float r1 = rsqrtf(ss1*(1.f/DIM) + 1e-6f);
  float hv[8]; float ss2 = 0.f;
#pragma unroll
  for(int i=0;i<8;i++){
    int idx = tid + i*256;
    hv[i] = hA[idx] + yv[i]*r1*g_pa[idx];
    ss2 += hv[i]*hv[i];
  }
  ss2 = blockSum256(ss2, red);
  float r2 = rsqrtf(ss2*(1.f/DIM) + 1e-6f);
#pragma unroll
  for(int i=0;i<8;i++){
    int idx = tid + i*256;
    xs[idx] = hv[i]*r2*g_pf[idx];
    if(blockIdx.x==0) hB[idx] = hv[i];
  }
  __syncthreads();
  int lane = tid & 63, wv = tid >> 6;
  int j = blockIdx.x*4 + wv;
  const float4* Gr = (const float4*)(Wg + (size_t)j*DIM);
  const float4* Ur = (const float4*)(Wu + (size_t)j*DIM);
  const float4* xs4 = (const float4*)xs;
  float ag = 0.f, au = 0.f;
#pragma unroll
  for(int i=0;i<DIM/256;i++){
    float4 bv = xs4[lane + i*64];
    ag += dot4(Gr[lane + i*64], bv);
    au += dot4(Ur[lane + i*64], bv);
  }
  ag = waveAllSum(ag);
  au = waveAllSum(au);
  if(lane==0) t[j] = gelu_tanh(ag)*au;
}

// ---- generic GEMV: y[r] = W[r,:] . x  (plain; used for down and plp) ----
template<int C>
__global__ __launch_bounds__(256) void gemv_k(const float* __restrict__ W,
    const float* __restrict__ x, float* __restrict__ y){
  __shared__ float xs[C];
  for(int i=threadIdx.x; i<C/4; i+=256)
    ((float4*)xs)[i] = ((const float4*)x)[i];
  __syncthreads();
  int lane = threadIdx.x & 63, wv = threadIdx.x >> 6;
  int r = blockIdx.x*4 + wv;
  const float4* Wr = (const float4*)(W + (size_t)r*C);
  const float4* xs4 = (const float4*)xs;
  float acc = 0.f;
#pragma unroll
  for(int i=0;i<C/256;i++) acc += dot4(Wr[lane + i*64], xs4[lane + i*64]);
  acc = waveAllSum(acc);
  if(lane==0) y[r] = acc;
}

// ---- plg GEMV with fused post_ff prologue ----
// hC = hB + rms(mv)*g_ff ; rows use hC directly (no rms); block0 persists hC
__global__ __launch_bounds__(256) void plg_k(const float* __restrict__ W,
    const float* __restrict__ mv, const float* __restrict__ hB,
    const float* __restrict__ g_ff, const float* __restrict__ pls,
    float* __restrict__ hCout, float* __restrict__ gb){
  __shared__ float xs[DIM];
  __shared__ float red[4];
  int tid = threadIdx.x;
  float mvv[8]; float ss1 = 0.f;
#pragma unroll
  for(int i=0;i<8;i++){ mvv[i] = mv[tid + i*256]; ss1 += mvv[i]*mvv[i]; }
  ss1 = blockSum256(ss1, red);
  float r1 = rsqrtf(ss1*(1.f/DIM) + 1e-6f);
#pragma unroll
  for(int i=0;i<8;i++){
    int idx = tid + i*256;
    float hc = hB[idx] + mvv[i]*r1*g_ff[idx];
    xs[idx] = hc;
    if(blockIdx.x==0) hCout[idx] = hc;
  }
  __syncthreads();
  int lane = tid & 63, wv = tid >> 6;
  int r = blockIdx.x*4 + wv;
  const float4* Wr = (const float4*)(W + (size_t)r*DIM);
  const float4* xs4 = (const float4*)xs;
  float acc = 0.f;
#pragma unroll
  for(int i=0;i<DIM/256;i++) acc += dot4(Wr[lane + i*64], xs4[lane + i*64]);
  acc = waveAllSum(acc);
  if(lane==0) gb[r] = gelu_tanh(acc)*pls[r];
}

// ---- final: out = (hC + rms(u)*g_pl)*ls ----
__global__ __launch_bounds__(256) void final_k(const float* __restrict__ u,
    const float* __restrict__ hC, const float* __restrict__ g_pl,
    const float* __restrict__ lsc, float* __restrict__ out){
  __shared__ float red[4];
  int tid = threadIdx.x;
  float uv[8]; float ss1 = 0.f;
#pragma unroll
  for(int i=0;i<8;i++){ uv[i] = u[tid + i*256]; ss1 += uv[i]*uv[i]; }
  ss1 = blockSum256(ss1, red);
  float r1 = rsqrtf(ss1*(1.f/DIM) + 1e-6f);
  float ls = lsc[0];
#pragma unroll
  for(int i=0;i<8;i++){
    int idx = tid + i*256;
    out[idx] = (hC[idx] + uv[i]*r1*g_pl[idx])*ls;
  }
}

extern "C" void kernel_launch(void* const* d_in, const int* in_sizes, int n_in,
                              void* d_out, int out_size, void* d_ws, size_t ws_size,
                              hipStream_t stream){
  const float* hidden   = (const float*)d_in[0];
  const float* plc      = (const float*)d_in[3];
  const float* cos_s    = (const float*)d_in[4];
  const float* sin_s    = (const float*)d_in[5];
  const float* cos_f    = (const float*)d_in[6];
  const float* sin_f    = (const float*)d_in[7];
  const float* K_in     = (const float*)d_in[8];
  const float* V_in     = (const float*)d_in[9];
  const float* w_q      = (const float*)d_in[10];
  const float* w_k      = (const float*)d_in[11];
  const float* w_v      = (const float*)d_in[12];
  const float* w_o      = (const float*)d_in[13];
  const float* g_in_ln  = (const float*)d_in[14];
  const float* g_q_norm = (const float*)d_in[15];
  const float* g_k_norm = (const float*)d_in[16];
  const float* g_pa_ln  = (const float*)d_in[17];
  const float* g_pf_ln  = (const float*)d_in[18];
  const float* g_ff_ln  = (const float*)d_in[19];
  const float* w_gate   = (const float*)d_in[20];
  const float* w_up     = (const float*)d_in[21];
  const float* w_down   = (const float*)d_in[22];
  const float* w_plg    = (const float*)d_in[23];
  const float* w_plp    = (const float*)d_in[24];
  const float* g_pl_ln  = (const float*)d_in[25];
  const float* l_scal   = (const float*)d_in[26];

  float* out  = (float*)d_out;
  float* outK = out + DIM;
  float* outV = outK + (size_t)NL*NKV*KVL*HD;

  float* ws   = (float*)d_ws;
  float* hA   = ws;
  float* hB   = ws + 2048;
  float* hC   = ws + 4096;
  float* qkv  = ws + 6144;
  float* y    = ws + 9216;
  float* t    = ws + 11264;
  float* mv   = ws + 19456;
  float* gb   = ws + 21504;
  float* u    = ws + 21760;
  float* pm   = ws + 23808;
  float* pl   = ws + 23936;
  float* po   = ws + 24064;

  (void)hipMemcpyAsync(outK, K_in, (size_t)NL*NKV*KVL*HD*sizeof(float),
                       hipMemcpyDeviceToDevice, stream);
  (void)hipMemcpyAsync(outV, V_in, (size_t)NL*NKV*KVL*HD*sizeof(float),
                       hipMemcpyDeviceToDevice, stream);

  for(int l=0;l<NL;l++){
    const float* cosT = (l==4) ? cos_f : cos_s;
    const float* sinT = (l==4) ? sin_f : sin_s;
    float* Kl = outK + (size_t)l*NKV*KVL*HD;
    float* Vl = outV + (size_t)l*NKV*KVL*HD;

    qkv_k<<<768,256,0,stream>>>(
        w_q + (size_t)l*NH*HD*DIM, w_k + (size_t)l*NKV*HD*DIM,
        w_v + (size_t)l*NKV*HD*DIM,
        hC, u,
        (l>0) ? g_pl_ln + (size_t)(l-1)*DIM : g_pl_ln,
        (l>0) ? l_scal + (l-1) : l_scal,
        g_in_ln + (size_t)l*DIM,
        (l==0) ? hidden : nullptr,
        hA, qkv);

    attn_k<<<NKV*NCH+1,256,0,stream>>>(qkv, g_q_norm + l*HD, g_k_norm + l*HD,
                                       cosT, sinT, Kl, Vl, pm, pl, po);

    wo_k<<<512,256,0,stream>>>(w_o + (size_t)l*DIM*NH*HD, pm, pl, po, y);

    gateup_k<<<FFI/4,256,0,stream>>>(w_gate + (size_t)l*FFI*DIM,
                                     w_up + (size_t)l*FFI*DIM,
                                     y, hA, g_pa_ln + (size_t)l*DIM,
                                     g_pf_ln + (size_t)l*DIM, hB, t);

    gemv_k<FFI><<<512,256,0,stream>>>(w_down + (size_t)l*DIM*FFI, t, mv);

    plg_k<<<PLD/4,256,0,stream>>>(w_plg + (size_t)l*PLD*DIM, mv, hB,
                                  g_ff_ln + (size_t)l*DIM, plc + l*PLD, hC, gb);

    gemv_k<PLD><<<512,256,0,stream>>>(w_plp + (size_t)l*DIM*PLD, gb, u);
  }

  final_k<<<1,256,0,stream>>>(u, hC, g_pl_ln + (size_t)(NL-1)*DIM,
                              l_scal + (NL-1), out);
}